// Round 16
// baseline (1231.947 us; speedup 1.0000x reference)
//
#include <hip/hip_runtime.h>
#include <hip/hip_fp16.h>
#include <stdint.h>

typedef _Float16 f16;
typedef float f32x4 __attribute__((ext_vector_type(4)));
typedef int i32x4v __attribute__((ext_vector_type(4)));
typedef int i32x8v __attribute__((ext_vector_type(8)));
typedef unsigned long long u64;

#define N_TOK 8192
#define VOCAB 8192
#define DIM   4096
#define DELTA 64.0f

// ---------------------------------------------------------------------------
__device__ __forceinline__ void gload16(const void* g, void* l) {
    __builtin_amdgcn_global_load_lds(
        (const __attribute__((address_space(1))) unsigned int*)(uintptr_t)g,
        (__attribute__((address_space(3))) unsigned int*)(uintptr_t)l,
        16, 0, 0);
}

__device__ __forceinline__ float keyinv(unsigned k) {
    unsigned b = (k & 0x80000000u) ? (k ^ 0x80000000u) : ~k;
    return __uint_as_float(b);
}

__device__ __forceinline__ void ins2(u64& k1, u64& k2, u64 v) {
    if (v < k1) { k2 = k1; k1 = v; }
    else if (v < k2) { k2 = v; }
}

// ---------------------------------------------------------------------------
// K_pack: fp8-e4m3 plane with 16B-unit permutation inside each 128B K-segment:
// canonical unit u (0..7) stored at unit p(u) = ((u&1)<<2)|(u>>1). Lane-group
// g's MX fragment (K bytes [32g,32g+32)) = canonical units {2g,2g+1} = packed
// units {g, 4+g} -> both b128 fragment reads hit the verified-0-conflict
// contiguous-unit pattern (R11/R12). Also enorms (f64 acc), counts=0.
__global__ __launch_bounds__(256) void k_pack(const float* __restrict__ inputs,
                                              const float* __restrict__ embedding,
                                              char* __restrict__ apk, char* __restrict__ bpk,
                                              float* __restrict__ enorms,
                                              int* __restrict__ counts) {
    int b = blockIdx.x, t = threadIdx.x;
    bool isB = b >= N_TOK;
    int row = isB ? b - N_TOK : b;
    const float* src = (isB ? embedding : inputs) + (size_t)row * DIM;
    char* dst = (isB ? bpk : apk) + (size_t)row * DIM;
    double nrm = 0.0;
#pragma unroll
    for (int k = 0; k < 4; k++) {
        int d0 = t * 4 + 1024 * k;
        float4 v = *(const float4*)(src + d0);
        nrm += (double)v.x * v.x + (double)v.y * v.y
             + (double)v.z * v.z + (double)v.w * v.w;
        int packed = 0;
        packed = __builtin_amdgcn_cvt_pk_fp8_f32(v.x, v.y, packed, false);
        packed = __builtin_amdgcn_cvt_pk_fp8_f32(v.z, v.w, packed, true);
        int c = d0 & 127;
        int u = c >> 4;
        int p = ((u & 1) << 2) | (u >> 1);
        *(int*)(dst + (d0 & ~127) + (p << 4) + (c & 15)) = packed;
    }
    if (isB) {
        __shared__ double red[256];
        red[t] = nrm;
        __syncthreads();
        for (int off = 128; off > 0; off >>= 1) {
            if (t < off) red[t] += red[t + off];
            __syncthreads();
        }
        if (t == 0) {
            enorms[row] = (float)red[0];
            counts[row] = 0;
        }
    }
}

// ---------------------------------------------------------------------------
// K_gemm (R16): R12/R15's measured-best 4-phase MX config with ONE fix:
// all 8 next-tile loads burst-issue at the top of the iteration (safe: nbuf's
// readers joined at the PREVIOUS iteration's P2-end barrier), and vmcnt(8)
// excludes exactly those 8 — so the wait targets tile-kt's loads, which now
// carry a full iteration (~15K cyc) of latency cover instead of R12's
// ISSUE2(6,7)-in-P2 pair that had only P3's few hundred cycles.
__global__ __launch_bounds__(512) void k_gemm(const char* __restrict__ apk,
                                              const char* __restrict__ bpk,
                                              const float* __restrict__ enorms,
                                              u64* __restrict__ cand) {
    extern __shared__ char lds[];             // 131072 B: 2 x (A 32KB | B 32KB)
    int b = blockIdx.x;
    int x = b & 7, l = b >> 3;                // XCD id, local 0..127
    int bm = x * 4 + ((l >> 3) & 3);          // XCD owns 4 bm rows
    int bn = (l >> 5) * 8 + (l & 7);          // sweep 8-bn stripes
    int tid = threadIdx.x;
    int lane = tid & 63, wid = tid >> 6;
    int wm = wid >> 2, wn = wid & 3;          // 2 x 4 waves; wave C = 128x64

    const char* srcs[8];
    unsigned lof[8];
#pragma unroll
    for (int e = 0; e < 8; e++) {
        int tile = e >> 2, q = e & 3;
        int s = q * 512 + tid;                 // 16B slot 0..2047 within matrix
        int r = s >> 3;                        // row 0..255 (128B rows)
        int c16 = (s & 7) ^ (r & 7);           // inverse swizzle on source
        int row = (tile ? bn : bm) * 256 + r;
        srcs[e] = (tile ? bpk : apk) + (size_t)row * DIM + c16 * 16;
        lof[e] = tile * 32768 + q * 8192 + wid * 1024;   // + lane*16 by HW
    }

    f32x4 acc[8][4];
#pragma unroll
    for (int m = 0; m < 8; m++)
#pragma unroll
        for (int n = 0; n < 4; n++) acc[m][n] = (f32x4){0.f, 0.f, 0.f, 0.f};

    const int g = lane >> 4;                  // lane group 0..3
    i32x8v a[4], b0[2], b1[2];

#define ISSUE8(buf) { _Pragma("unroll") for (int e = 0; e < 8; e++) { \
        gload16(srcs[e], &lds[(buf) + lof[e]]); srcs[e] += 128; } }
#define LDA(mh) { _Pragma("unroll") for (int m = 0; m < 4; m++) { \
        int r = wm * 128 + (mh) * 64 + m * 16 + (lane & 15); \
        i32x4v lo = *(const i32x4v*)&lds[cur + r * 128 + ((g ^ (r & 7)) << 4)]; \
        i32x4v hi = *(const i32x4v*)&lds[cur + r * 128 + (((4 + g) ^ (r & 7)) << 4)]; \
        a[m] = __builtin_shufflevector(lo, hi, 0, 1, 2, 3, 4, 5, 6, 7); } }
#define LDB(bb, nh) { _Pragma("unroll") for (int n = 0; n < 2; n++) { \
        int r = wn * 64 + (nh) * 32 + n * 16 + (lane & 15); \
        i32x4v lo = *(const i32x4v*)&lds[cur + 32768 + r * 128 + ((g ^ (r & 7)) << 4)]; \
        i32x4v hi = *(const i32x4v*)&lds[cur + 32768 + r * 128 + (((4 + g) ^ (r & 7)) << 4)]; \
        bb[n] = __builtin_shufflevector(lo, hi, 0, 1, 2, 3, 4, 5, 6, 7); } }
#define QUAD(mh, nh, bb) { _Pragma("unroll") for (int m = 0; m < 4; m++) \
        _Pragma("unroll") for (int n = 0; n < 2; n++) \
        acc[(mh) * 4 + m][(nh) * 2 + n] = __builtin_amdgcn_mfma_scale_f32_16x16x128_f8f6f4( \
            a[m], bb[n], acc[(mh) * 4 + m][(nh) * 2 + n], 0, 0, \
            0, 0x7F7F7F7F, 0, 0x7F7F7F7F); }
#define BARRIER() __builtin_amdgcn_s_barrier()
#define LGKM0() { asm volatile("s_waitcnt lgkmcnt(0)" ::: "memory"); \
                  __builtin_amdgcn_sched_barrier(0); }

    ISSUE8(0u);   // prologue: tile 0 -> buf 0 (8 loads in flight)

    for (int kt = 0; kt < 32; ++kt) {
        const unsigned cur = (kt & 1) ? 65536u : 0u;
        const unsigned nbuf = cur ^ 65536u;
        // top: burst-issue ALL 8 loads for tile kt+1 (nbuf's readers joined at
        // the previous iteration's P2-end barrier), then wait for tile kt's 8
        // (full-iteration cover -> near-free wait).
        if (kt < 31) {
            ISSUE8(nbuf);
            asm volatile("s_waitcnt vmcnt(8)" ::: "memory");
        } else {
            asm volatile("s_waitcnt vmcnt(0)" ::: "memory");
        }
        __builtin_amdgcn_sched_barrier(0);
        BARRIER();
        // P0: quadrant (0,0)
        LDA(0); LDB(b0, 0);
        BARRIER(); LGKM0();
        __builtin_amdgcn_s_setprio(1); QUAD(0, 0, b0); __builtin_amdgcn_s_setprio(0);
        BARRIER();
        // P1: quadrant (0,1)
        LDB(b1, 1);
        BARRIER(); LGKM0();
        __builtin_amdgcn_s_setprio(1); QUAD(0, 1, b1); __builtin_amdgcn_s_setprio(0);
        BARRIER();
        // P2: quadrant (1,0) (reuses b0)
        LDA(1);
        BARRIER(); LGKM0();
        __builtin_amdgcn_s_setprio(1); QUAD(1, 0, b0); __builtin_amdgcn_s_setprio(0);
        BARRIER();   // joins all waves' last reads of cur before next top stages into it
        // P3: quadrant (1,1) — register-only
        __builtin_amdgcn_s_setprio(1); QUAD(1, 1, b1); __builtin_amdgcn_s_setprio(0);
    }
#undef ISSUE8
#undef LDA
#undef LDB
#undef QUAD
#undef BARRIER
#undef LGKM0

    float en[4];
    int colb = bn * 256 + wn * 64 + (lane & 15);
#pragma unroll
    for (int n = 0; n < 4; n++) en[n] = enorms[colb + n * 16];
#pragma unroll
    for (int M = 0; M < 8; M++) {
#pragma unroll
        for (int reg = 0; reg < 4; reg++) {
            u64 k1 = ~0ull, k2 = ~0ull;
#pragma unroll
            for (int n = 0; n < 4; n++) {
                float d = en[n] - 2.0f * acc[M][n][reg];
                unsigned bb = __float_as_uint(d);
                unsigned key = (bb & 0x80000000u) ? ~bb : (bb | 0x80000000u);
                ins2(k1, k2, ((u64)key << 32) | (unsigned)(colb + n * 16));
            }
#pragma unroll
            for (int msk = 1; msk < 16; msk <<= 1) {
                u64 o1 = __shfl_xor(k1, msk, 64);
                u64 o2 = __shfl_xor(k2, msk, 64);
                ins2(k1, k2, o1);
                ins2(k1, k2, o2);
            }
            if ((lane & 15) == 0) {
                int rowg = bm * 256 + wm * 128 + M * 16 + ((lane >> 4) << 2) + reg;
                size_t slot = ((size_t)rowg * 32 + bn) * 4 + wn;
                ulonglong2 v; v.x = k1; v.y = k2;
                *(ulonglong2*)&cand[slot * 2] = v;
            }
        }
    }
}

// ---------------------------------------------------------------------------
// K_cand: per token, min over 256 stored entries; collect candidates within
// DELTA; exact f32 recheck (float4 loads, per-wave partials, ONE barrier);
// fused quantize-copy + loss partial + count. (R12 verbatim.)
__global__ __launch_bounds__(256) void k_cand(const u64* __restrict__ cand,
                                              const float* __restrict__ enorms,
                                              const float* __restrict__ inputs,
                                              const float* __restrict__ embedding,
                                              float* __restrict__ o_idx,
                                              float* __restrict__ o_quant,
                                              float* __restrict__ partials,
                                              int* __restrict__ counts) {
    int tok = blockIdx.x, t = threadIdx.x;
    int lane = t & 63, w = t >> 6;
    __shared__ u64 redu[4];
    __shared__ float redf[4];
    __shared__ float pdot[64][4];
    __shared__ int clist[64];
    __shared__ int s_cnt;
    if (t == 0) s_cnt = 0;
    u64 e = cand[(size_t)tok * 256 + t];
    u64 v = e;
#pragma unroll
    for (int msk = 1; msk < 64; msk <<= 1) {
        u64 o = __shfl_xor(v, msk, 64);
        if (o < v) v = o;
    }
    if (lane == 0) redu[w] = v;
    __syncthreads();
    u64 m01 = redu[0] < redu[1] ? redu[0] : redu[1];
    u64 m23 = redu[2] < redu[3] ? redu[2] : redu[3];
    u64 mall = m01 < m23 ? m01 : m23;
    float dmin = keyinv((unsigned)(mall >> 32));
    float myd = keyinv((unsigned)(e >> 32));
    if (myd <= dmin + DELTA) {
        int p = atomicAdd(&s_cnt, 1);
        if (p < 64) clist[p] = (int)(unsigned)(e & 0xffffffffu);
    }
    __syncthreads();
    int nc = min(s_cnt, 64);

    const float* xrow = inputs + (size_t)tok * DIM;
    float4 xr4[4];
#pragma unroll
    for (int k = 0; k < 4; k++) xr4[k] = *(const float4*)(xrow + t * 4 + 1024 * k);

    for (int i = 0; i < nc; i++) {
        int c = clist[i];
        const float* erow = embedding + (size_t)c * DIM;
        float p = 0.f;
#pragma unroll
        for (int k = 0; k < 4; k++) {
            float4 e4 = *(const float4*)(erow + t * 4 + 1024 * k);
            p += xr4[k].x * e4.x + xr4[k].y * e4.y + xr4[k].z * e4.z + xr4[k].w * e4.w;
        }
#pragma unroll
        for (int msk = 1; msk < 64; msk <<= 1) p += __shfl_xor(p, msk, 64);
        if (lane == 0) pdot[i][w] = p;
    }
    __syncthreads();   // the ONE barrier

    float best = 3.4e38f;
    int bcol = 0x7fffffff;
    for (int i = 0; i < nc; i++) {
        int c = clist[i];
        float dot = (pdot[i][0] + pdot[i][1]) + (pdot[i][2] + pdot[i][3]);
        float dist = enorms[c] - 2.0f * dot;
        if (dist < best || (dist == best && c < bcol)) { best = dist; bcol = c; }
    }
    const float* eb = embedding + (size_t)bcol * DIM;
    float* qrow = o_quant + (size_t)tok * DIM;   // 4B-misaligned region: scalar stores
    float ls = 0.f;
#pragma unroll
    for (int k = 0; k < 4; k++) {
        int d = t * 4 + 1024 * k;
        float4 q4 = *(const float4*)(eb + d);
        qrow[d + 0] = q4.x; qrow[d + 1] = q4.y; qrow[d + 2] = q4.z; qrow[d + 3] = q4.w;
        float dx = q4.x - xr4[k].x, dy = q4.y - xr4[k].y;
        float dz = q4.z - xr4[k].z, dw = q4.w - xr4[k].w;
        ls += dx * dx + dy * dy + dz * dz + dw * dw;
    }
#pragma unroll
    for (int msk = 1; msk < 64; msk <<= 1) ls += __shfl_xor(ls, msk, 64);
    if (lane == 0) redf[w] = ls;
    __syncthreads();
    if (t == 0) {
        partials[tok] = (redf[0] + redf[1]) + (redf[2] + redf[3]);
        o_idx[tok] = (float)bcol;
        atomicAdd(&counts[bcol], 1);
    }
}

// ---------------------------------------------------------------------------
// K_csloss: block 0 = cluster-size EMA + perplexity; block 1 = loss reduce.
__global__ __launch_bounds__(1024) void k_csloss(const int* __restrict__ counts,
                                                 const float* __restrict__ ema_cs,
                                                 const float* __restrict__ partials,
                                                 float* __restrict__ o_ncs,
                                                 float* __restrict__ o_perp,
                                                 float* __restrict__ o_loss) {
    __shared__ float red[1024];
    int t = threadIdx.x;
    if (blockIdx.x == 1) {
        float s = 0.f;
#pragma unroll
        for (int k = 0; k < 8; k++) s += partials[t * 8 + k];
        red[t] = s;
        __syncthreads();
        for (int off = 512; off > 0; off >>= 1) {
            if (t < off) red[t] += red[t + off];
            __syncthreads();
        }
        if (t == 0) o_loss[0] = 0.25f * red[0] / ((float)N_TOK * (float)DIM);
        return;
    }
    float pre[8];
    float psum = 0.f, esum = 0.f;
#pragma unroll
    for (int k = 0; k < 8; k++) {
        int j = t * 8 + k;
        float c = (float)counts[j];
        float p = ema_cs[j] * 0.99f + 0.01f * c;
        pre[k] = p;
        psum += p;
        float ap = c * (1.0f / 8192.0f);
        esum += ap * logf(ap + 1e-10f);
    }
    red[t] = psum;
    __syncthreads();
    for (int off = 512; off > 0; off >>= 1) {
        if (t < off) red[t] += red[t + off];
        __syncthreads();
    }
    float n = red[0];
    __syncthreads();
    red[t] = esum;
    __syncthreads();
    for (int off = 512; off > 0; off >>= 1) {
        if (t < off) red[t] += red[t + off];
        __syncthreads();
    }
    if (t == 0) o_perp[0] = expf(-red[0]);
    float scale = n / (n + (float)VOCAB * 1e-5f);
#pragma unroll
    for (int k = 0; k < 8; k++) {
        int j = t * 8 + k;
        o_ncs[j] = (pre[k] + 1e-5f) * scale;
    }
}

// ---------------------------------------------------------------------------
// K_ema (R15-proven): o_idx staged once into LDS, wave-shuffle prefix scan
// (3 barriers), float4 gather-sum + EMA math.
__global__ __launch_bounds__(256) void k_ema(const float* __restrict__ o_idx,
                                             const float* __restrict__ inputs,
                                             const float* __restrict__ ema_w,
                                             const float* __restrict__ o_ncs,
                                             float* __restrict__ o_neww,
                                             float* __restrict__ o_newemb) {
    int j = blockIdx.x, t = threadIdx.x;
    int lane = t & 63, w = t >> 6;
    __shared__ int idxs[8192];     // 32KB
    __shared__ int list[256];
    __shared__ int wsum[4];
#pragma unroll
    for (int k = 0; k < 8; k++) {
        int base = t * 4 + 1024 * k;
        float4 v = *(const float4*)(o_idx + base);
        idxs[base + 0] = (int)v.x; idxs[base + 1] = (int)v.y;
        idxs[base + 2] = (int)v.z; idxs[base + 3] = (int)v.w;
    }
    __syncthreads();
    int c = 0;
#pragma unroll
    for (int k = 0; k < 32; k++) c += (idxs[t * 32 + k] == j);
    int v = c;
#pragma unroll
    for (int off = 1; off < 64; off <<= 1) {
        int o = __shfl_up(v, off, 64);
        if (lane >= off) v += o;
    }
    if (lane == 63) wsum[w] = v;
    __syncthreads();
    int wbase = 0;
#pragma unroll
    for (int i = 0; i < 4; i++) wbase += (i < w) ? wsum[i] : 0;
    int excl = wbase + v - c;
    int total = ((wsum[0] + wsum[1]) + (wsum[2] + wsum[3]));
    int pos = excl;
    for (int k = 0; k < 32; k++) {
        int tok = t * 32 + k;
        if (idxs[tok] == j && pos < 256) list[pos++] = tok;
    }
    __syncthreads();
    if (total > 256) total = 256;
    float nc = o_ncs[j];
    size_t rowoff = (size_t)j * DIM;
#pragma unroll
    for (int k = 0; k < 4; k++) {
        int d = t * 4 + 1024 * k;
        float sx = 0.f, sy = 0.f, sz = 0.f, sw = 0.f;
        for (int q = 0; q < total; q++) {
            float4 vv = *(const float4*)(inputs + (size_t)list[q] * DIM + d);
            sx += vv.x; sy += vv.y; sz += vv.z; sw += vv.w;
        }
        float4 w4 = *(const float4*)(ema_w + rowoff + d);
        float w0 = w4.x * 0.99f + 0.01f * sx;
        float w1 = w4.y * 0.99f + 0.01f * sy;
        float w2 = w4.z * 0.99f + 0.01f * sz;
        float w3 = w4.w * 0.99f + 0.01f * sw;
        o_neww[rowoff + d + 0] = w0; o_newemb[rowoff + d + 0] = w0 / nc;
        o_neww[rowoff + d + 1] = w1; o_newemb[rowoff + d + 1] = w1 / nc;
        o_neww[rowoff + d + 2] = w2; o_newemb[rowoff + d + 2] = w2 / nc;
        o_neww[rowoff + d + 3] = w3; o_newemb[rowoff + d + 3] = w3 / nc;
    }
}

// ---------------------------------------------------------------------------
extern "C" void kernel_launch(void* const* d_in, const int* in_sizes, int n_in,
                              void* d_out, int out_size, void* d_ws, size_t ws_size,
                              hipStream_t stream) {
    const float* inputs    = (const float*)d_in[0];
    const float* embedding = (const float*)d_in[1];
    const float* ema_w     = (const float*)d_in[2];
    const float* ema_cs    = (const float*)d_in[3];

    float* out = (float*)d_out;
    char* base = (char*)d_out;

    // scratch carved from d_out (lifetime-checked):
    // apk/bpk (fp8, 32MB each) dead after k_gemm; cand/enorms/counts/partials
    // parked inside o_neww region (written only by k_ema, last kernel).
    char* apk       = base;                            // [0, 32M)
    char* bpk       = base + 33554432;                 // [32M, 64M)
    u64* cand       = (u64*)(base + 167772160);        // 16 MB, dead after k_cand
    float* enorms   = (float*)(base + 184549376);      // 32 KB, dead after k_cand
    int* counts     = (int*)(base + 184582144);        // 32 KB, dead after k_csloss
    float* partials = (float*)(base + 184614912);      // 32 KB, dead after k_csloss

    // output regions (element offsets, return order)
    float* o_loss   = out;                 // [1]
    float* o_quant  = out + 1;             // [8192*4096]
    float* o_perp   = out + 33554433;      // [1]
    float* o_idx    = out + 33554434;      // [8192]
    float* o_ncs    = out + 33562626;      // [8192]
    float* o_neww   = out + 33570818;      // [8192*4096]
    float* o_newemb = out + 67125250;      // [8192*4096]

    k_pack<<<dim3(N_TOK + VOCAB), dim3(256), 0, stream>>>(inputs, embedding, apk, bpk,
                                                          enorms, counts);
    k_gemm<<<dim3(1024), dim3(512), 131072, stream>>>(apk, bpk, enorms, cand);
    k_cand<<<dim3(N_TOK), dim3(256), 0, stream>>>(cand, enorms, inputs, embedding,
                                                  o_idx, o_quant, partials, counts);
    k_csloss<<<dim3(2), dim3(1024), 0, stream>>>(counts, ema_cs, partials,
                                                 o_ncs, o_perp, o_loss);
    k_ema<<<dim3(VOCAB), dim3(256), 0, stream>>>(o_idx, inputs, ema_w, o_ncs, o_neww, o_newemb);
}

// Round 17
// 1201.984 us; speedup vs baseline: 1.0249x; 1.0249x over previous
//
#include <hip/hip_runtime.h>
#include <hip/hip_fp16.h>
#include <stdint.h>

typedef _Float16 f16;
typedef float f32x4 __attribute__((ext_vector_type(4)));
typedef int i32x4v __attribute__((ext_vector_type(4)));
typedef int i32x8v __attribute__((ext_vector_type(8)));
typedef unsigned long long u64;

#define N_TOK 8192
#define VOCAB 8192
#define DIM   4096
#define DELTA 64.0f

// ---------------------------------------------------------------------------
__device__ __forceinline__ void gload16(const void* g, void* l) {
    __builtin_amdgcn_global_load_lds(
        (const __attribute__((address_space(1))) unsigned int*)(uintptr_t)g,
        (__attribute__((address_space(3))) unsigned int*)(uintptr_t)l,
        16, 0, 0);
}

__device__ __forceinline__ float keyinv(unsigned k) {
    unsigned b = (k & 0x80000000u) ? (k ^ 0x80000000u) : ~k;
    return __uint_as_float(b);
}

__device__ __forceinline__ void ins2(u64& k1, u64& k2, u64 v) {
    if (v < k1) { k2 = k1; k1 = v; }
    else if (v < k2) { k2 = v; }
}

// ---------------------------------------------------------------------------
// K_pack: fp8-e4m3 plane with 16B-unit permutation inside each 128B K-segment:
// canonical unit u (0..7) stored at unit p(u) = ((u&1)<<2)|(u>>1). Lane-group
// g's MX fragment (K bytes [32g,32g+32)) = canonical units {2g,2g+1} = packed
// units {g, 4+g} -> both b128 fragment reads hit the verified-0-conflict
// contiguous-unit pattern (R11/R12). Also enorms (f64 acc), counts=0.
__global__ __launch_bounds__(256) void k_pack(const float* __restrict__ inputs,
                                              const float* __restrict__ embedding,
                                              char* __restrict__ apk, char* __restrict__ bpk,
                                              float* __restrict__ enorms,
                                              int* __restrict__ counts) {
    int b = blockIdx.x, t = threadIdx.x;
    bool isB = b >= N_TOK;
    int row = isB ? b - N_TOK : b;
    const float* src = (isB ? embedding : inputs) + (size_t)row * DIM;
    char* dst = (isB ? bpk : apk) + (size_t)row * DIM;
    double nrm = 0.0;
#pragma unroll
    for (int k = 0; k < 4; k++) {
        int d0 = t * 4 + 1024 * k;
        float4 v = *(const float4*)(src + d0);
        nrm += (double)v.x * v.x + (double)v.y * v.y
             + (double)v.z * v.z + (double)v.w * v.w;
        int packed = 0;
        packed = __builtin_amdgcn_cvt_pk_fp8_f32(v.x, v.y, packed, false);
        packed = __builtin_amdgcn_cvt_pk_fp8_f32(v.z, v.w, packed, true);
        int c = d0 & 127;
        int u = c >> 4;
        int p = ((u & 1) << 2) | (u >> 1);
        *(int*)(dst + (d0 & ~127) + (p << 4) + (c & 15)) = packed;
    }
    if (isB) {
        __shared__ double red[256];
        red[t] = nrm;
        __syncthreads();
        for (int off = 128; off > 0; off >>= 1) {
            if (t < off) red[t] += red[t + off];
            __syncthreads();
        }
        if (t == 0) {
            enorms[row] = (float)red[0];
            counts[row] = 0;
        }
    }
}

// ---------------------------------------------------------------------------
// K_gemm (R17 = R12/R15 verbatim, the measured-best 845us config): 8-wave
// 256x256 4-phase schedule, fp8 MX K=128, spread 2-load-per-phase issue,
// counted vmcnt(2), XCD supertile, 0-conflict fragment reads.
// Epilogue: top-2 (key|col) per (row, 64-col slice).
__global__ __launch_bounds__(512) void k_gemm(const char* __restrict__ apk,
                                              const char* __restrict__ bpk,
                                              const float* __restrict__ enorms,
                                              u64* __restrict__ cand) {
    extern __shared__ char lds[];             // 131072 B: 2 x (A 32KB | B 32KB)
    int b = blockIdx.x;
    int x = b & 7, l = b >> 3;                // XCD id, local 0..127
    int bm = x * 4 + ((l >> 3) & 3);          // XCD owns 4 bm rows
    int bn = (l >> 5) * 8 + (l & 7);          // sweep 8-bn stripes
    int tid = threadIdx.x;
    int lane = tid & 63, wid = tid >> 6;
    int wm = wid >> 2, wn = wid & 3;          // 2 x 4 waves; wave C = 128x64

    const char* srcs[8];
    unsigned lof[8];
#pragma unroll
    for (int e = 0; e < 8; e++) {
        int tile = e >> 2, q = e & 3;
        int s = q * 512 + tid;                 // 16B slot 0..2047 within matrix
        int r = s >> 3;                        // row 0..255 (128B rows)
        int c16 = (s & 7) ^ (r & 7);           // inverse swizzle on source
        int row = (tile ? bn : bm) * 256 + r;
        srcs[e] = (tile ? bpk : apk) + (size_t)row * DIM + c16 * 16;
        lof[e] = tile * 32768 + q * 8192 + wid * 1024;   // + lane*16 by HW
    }

    f32x4 acc[8][4];
#pragma unroll
    for (int m = 0; m < 8; m++)
#pragma unroll
        for (int n = 0; n < 4; n++) acc[m][n] = (f32x4){0.f, 0.f, 0.f, 0.f};

    const int g = lane >> 4;                  // lane group 0..3
    i32x8v a[4], b0[2], b1[2];

#define ISSUE2(eA, eB) { gload16(srcs[eA], &lds[nbuf + lof[eA]]); srcs[eA] += 128; \
                         gload16(srcs[eB], &lds[nbuf + lof[eB]]); srcs[eB] += 128; }
#define LDA(mh) { _Pragma("unroll") for (int m = 0; m < 4; m++) { \
        int r = wm * 128 + (mh) * 64 + m * 16 + (lane & 15); \
        i32x4v lo = *(const i32x4v*)&lds[cur + r * 128 + ((g ^ (r & 7)) << 4)]; \
        i32x4v hi = *(const i32x4v*)&lds[cur + r * 128 + (((4 + g) ^ (r & 7)) << 4)]; \
        a[m] = __builtin_shufflevector(lo, hi, 0, 1, 2, 3, 4, 5, 6, 7); } }
#define LDB(bb, nh) { _Pragma("unroll") for (int n = 0; n < 2; n++) { \
        int r = wn * 64 + (nh) * 32 + n * 16 + (lane & 15); \
        i32x4v lo = *(const i32x4v*)&lds[cur + 32768 + r * 128 + ((g ^ (r & 7)) << 4)]; \
        i32x4v hi = *(const i32x4v*)&lds[cur + 32768 + r * 128 + (((4 + g) ^ (r & 7)) << 4)]; \
        bb[n] = __builtin_shufflevector(lo, hi, 0, 1, 2, 3, 4, 5, 6, 7); } }
#define QUAD(mh, nh, bb) { _Pragma("unroll") for (int m = 0; m < 4; m++) \
        _Pragma("unroll") for (int n = 0; n < 2; n++) \
        acc[(mh) * 4 + m][(nh) * 2 + n] = __builtin_amdgcn_mfma_scale_f32_16x16x128_f8f6f4( \
            a[m], bb[n], acc[(mh) * 4 + m][(nh) * 2 + n], 0, 0, \
            0, 0x7F7F7F7F, 0, 0x7F7F7F7F); }
#define BARRIER() __builtin_amdgcn_s_barrier()
#define LGKM0() { asm volatile("s_waitcnt lgkmcnt(0)" ::: "memory"); \
                  __builtin_amdgcn_sched_barrier(0); }

    {
        const unsigned nbuf = 0u;
        ISSUE2(0, 1); ISSUE2(2, 3); ISSUE2(4, 5); ISSUE2(6, 7);
    }

    for (int kt = 0; kt < 32; ++kt) {
        const unsigned cur = (kt & 1) ? 65536u : 0u;
        const unsigned nbuf = cur ^ 65536u;
        if (kt < 31) {
            ISSUE2(0, 1);
            asm volatile("s_waitcnt vmcnt(2)" ::: "memory");
        } else {
            asm volatile("s_waitcnt vmcnt(0)" ::: "memory");
        }
        __builtin_amdgcn_sched_barrier(0);
        BARRIER();
        // P0: quadrant (0,0)
        LDA(0); LDB(b0, 0);
        if (kt < 31) ISSUE2(2, 3);
        BARRIER(); LGKM0();
        __builtin_amdgcn_s_setprio(1); QUAD(0, 0, b0); __builtin_amdgcn_s_setprio(0);
        BARRIER();
        // P1: quadrant (0,1)
        LDB(b1, 1);
        if (kt < 31) ISSUE2(4, 5);
        BARRIER(); LGKM0();
        __builtin_amdgcn_s_setprio(1); QUAD(0, 1, b1); __builtin_amdgcn_s_setprio(0);
        BARRIER();
        // P2: quadrant (1,0) (reuses b0)
        LDA(1);
        if (kt < 31) ISSUE2(6, 7);
        BARRIER(); LGKM0();
        __builtin_amdgcn_s_setprio(1); QUAD(1, 0, b0); __builtin_amdgcn_s_setprio(0);
        BARRIER();   // guards cur's LDS reads before next top stages into it
        // P3: quadrant (1,1) — register-only
        __builtin_amdgcn_s_setprio(1); QUAD(1, 1, b1); __builtin_amdgcn_s_setprio(0);
    }
#undef ISSUE2
#undef LDA
#undef LDB
#undef QUAD
#undef BARRIER
#undef LGKM0

    float en[4];
    int colb = bn * 256 + wn * 64 + (lane & 15);
#pragma unroll
    for (int n = 0; n < 4; n++) en[n] = enorms[colb + n * 16];
#pragma unroll
    for (int M = 0; M < 8; M++) {
#pragma unroll
        for (int reg = 0; reg < 4; reg++) {
            u64 k1 = ~0ull, k2 = ~0ull;
#pragma unroll
            for (int n = 0; n < 4; n++) {
                float d = en[n] - 2.0f * acc[M][n][reg];
                unsigned bb = __float_as_uint(d);
                unsigned key = (bb & 0x80000000u) ? ~bb : (bb | 0x80000000u);
                ins2(k1, k2, ((u64)key << 32) | (unsigned)(colb + n * 16));
            }
#pragma unroll
            for (int msk = 1; msk < 16; msk <<= 1) {
                u64 o1 = __shfl_xor(k1, msk, 64);
                u64 o2 = __shfl_xor(k2, msk, 64);
                ins2(k1, k2, o1);
                ins2(k1, k2, o2);
            }
            if ((lane & 15) == 0) {
                int rowg = bm * 256 + wm * 128 + M * 16 + ((lane >> 4) << 2) + reg;
                size_t slot = ((size_t)rowg * 32 + bn) * 4 + wn;
                ulonglong2 v; v.x = k1; v.y = k2;
                *(ulonglong2*)&cand[slot * 2] = v;
            }
        }
    }
}

// ---------------------------------------------------------------------------
// K_cand: per token, min over 256 stored entries; collect candidates within
// DELTA; exact f32 recheck (float4 loads, per-wave partials, ONE barrier);
// fused quantize-copy + loss partial + count. (R12 verbatim.)
__global__ __launch_bounds__(256) void k_cand(const u64* __restrict__ cand,
                                              const float* __restrict__ enorms,
                                              const float* __restrict__ inputs,
                                              const float* __restrict__ embedding,
                                              float* __restrict__ o_idx,
                                              float* __restrict__ o_quant,
                                              float* __restrict__ partials,
                                              int* __restrict__ counts) {
    int tok = blockIdx.x, t = threadIdx.x;
    int lane = t & 63, w = t >> 6;
    __shared__ u64 redu[4];
    __shared__ float redf[4];
    __shared__ float pdot[64][4];
    __shared__ int clist[64];
    __shared__ int s_cnt;
    if (t == 0) s_cnt = 0;
    u64 e = cand[(size_t)tok * 256 + t];
    u64 v = e;
#pragma unroll
    for (int msk = 1; msk < 64; msk <<= 1) {
        u64 o = __shfl_xor(v, msk, 64);
        if (o < v) v = o;
    }
    if (lane == 0) redu[w] = v;
    __syncthreads();
    u64 m01 = redu[0] < redu[1] ? redu[0] : redu[1];
    u64 m23 = redu[2] < redu[3] ? redu[2] : redu[3];
    u64 mall = m01 < m23 ? m01 : m23;
    float dmin = keyinv((unsigned)(mall >> 32));
    float myd = keyinv((unsigned)(e >> 32));
    if (myd <= dmin + DELTA) {
        int p = atomicAdd(&s_cnt, 1);
        if (p < 64) clist[p] = (int)(unsigned)(e & 0xffffffffu);
    }
    __syncthreads();
    int nc = min(s_cnt, 64);

    const float* xrow = inputs + (size_t)tok * DIM;
    float4 xr4[4];
#pragma unroll
    for (int k = 0; k < 4; k++) xr4[k] = *(const float4*)(xrow + t * 4 + 1024 * k);

    for (int i = 0; i < nc; i++) {
        int c = clist[i];
        const float* erow = embedding + (size_t)c * DIM;
        float p = 0.f;
#pragma unroll
        for (int k = 0; k < 4; k++) {
            float4 e4 = *(const float4*)(erow + t * 4 + 1024 * k);
            p += xr4[k].x * e4.x + xr4[k].y * e4.y + xr4[k].z * e4.z + xr4[k].w * e4.w;
        }
#pragma unroll
        for (int msk = 1; msk < 64; msk <<= 1) p += __shfl_xor(p, msk, 64);
        if (lane == 0) pdot[i][w] = p;
    }
    __syncthreads();   // the ONE barrier

    float best = 3.4e38f;
    int bcol = 0x7fffffff;
    for (int i = 0; i < nc; i++) {
        int c = clist[i];
        float dot = (pdot[i][0] + pdot[i][1]) + (pdot[i][2] + pdot[i][3]);
        float dist = enorms[c] - 2.0f * dot;
        if (dist < best || (dist == best && c < bcol)) { best = dist; bcol = c; }
    }
    const float* eb = embedding + (size_t)bcol * DIM;
    float* qrow = o_quant + (size_t)tok * DIM;   // 4B-misaligned region: scalar stores
    float ls = 0.f;
#pragma unroll
    for (int k = 0; k < 4; k++) {
        int d = t * 4 + 1024 * k;
        float4 q4 = *(const float4*)(eb + d);
        qrow[d + 0] = q4.x; qrow[d + 1] = q4.y; qrow[d + 2] = q4.z; qrow[d + 3] = q4.w;
        float dx = q4.x - xr4[k].x, dy = q4.y - xr4[k].y;
        float dz = q4.z - xr4[k].z, dw = q4.w - xr4[k].w;
        ls += dx * dx + dy * dy + dz * dz + dw * dw;
    }
#pragma unroll
    for (int msk = 1; msk < 64; msk <<= 1) ls += __shfl_xor(ls, msk, 64);
    if (lane == 0) redf[w] = ls;
    __syncthreads();
    if (t == 0) {
        partials[tok] = (redf[0] + redf[1]) + (redf[2] + redf[3]);
        o_idx[tok] = (float)bcol;
        atomicAdd(&counts[bcol], 1);
    }
}

// ---------------------------------------------------------------------------
// K_csloss: block 0 = cluster-size EMA + perplexity; block 1 = loss reduce.
__global__ __launch_bounds__(1024) void k_csloss(const int* __restrict__ counts,
                                                 const float* __restrict__ ema_cs,
                                                 const float* __restrict__ partials,
                                                 float* __restrict__ o_ncs,
                                                 float* __restrict__ o_perp,
                                                 float* __restrict__ o_loss) {
    __shared__ float red[1024];
    int t = threadIdx.x;
    if (blockIdx.x == 1) {
        float s = 0.f;
#pragma unroll
        for (int k = 0; k < 8; k++) s += partials[t * 8 + k];
        red[t] = s;
        __syncthreads();
        for (int off = 512; off > 0; off >>= 1) {
            if (t < off) red[t] += red[t + off];
            __syncthreads();
        }
        if (t == 0) o_loss[0] = 0.25f * red[0] / ((float)N_TOK * (float)DIM);
        return;
    }
    float pre[8];
    float psum = 0.f, esum = 0.f;
#pragma unroll
    for (int k = 0; k < 8; k++) {
        int j = t * 8 + k;
        float c = (float)counts[j];
        float p = ema_cs[j] * 0.99f + 0.01f * c;
        pre[k] = p;
        psum += p;
        float ap = c * (1.0f / 8192.0f);
        esum += ap * logf(ap + 1e-10f);
    }
    red[t] = psum;
    __syncthreads();
    for (int off = 512; off > 0; off >>= 1) {
        if (t < off) red[t] += red[t + off];
        __syncthreads();
    }
    float n = red[0];
    __syncthreads();
    red[t] = esum;
    __syncthreads();
    for (int off = 512; off > 0; off >>= 1) {
        if (t < off) red[t] += red[t + off];
        __syncthreads();
    }
    if (t == 0) o_perp[0] = expf(-red[0]);
    float scale = n / (n + (float)VOCAB * 1e-5f);
#pragma unroll
    for (int k = 0; k < 8; k++) {
        int j = t * 8 + k;
        o_ncs[j] = (pre[k] + 1e-5f) * scale;
    }
}

// ---------------------------------------------------------------------------
// K_ema (R15-proven): o_idx staged once into LDS, wave-shuffle prefix scan
// (3 barriers), float4 gather-sum + EMA math.
__global__ __launch_bounds__(256) void k_ema(const float* __restrict__ o_idx,
                                             const float* __restrict__ inputs,
                                             const float* __restrict__ ema_w,
                                             const float* __restrict__ o_ncs,
                                             float* __restrict__ o_neww,
                                             float* __restrict__ o_newemb) {
    int j = blockIdx.x, t = threadIdx.x;
    int lane = t & 63, w = t >> 6;
    __shared__ int idxs[8192];     // 32KB
    __shared__ int list[256];
    __shared__ int wsum[4];
#pragma unroll
    for (int k = 0; k < 8; k++) {
        int base = t * 4 + 1024 * k;
        float4 v = *(const float4*)(o_idx + base);
        idxs[base + 0] = (int)v.x; idxs[base + 1] = (int)v.y;
        idxs[base + 2] = (int)v.z; idxs[base + 3] = (int)v.w;
    }
    __syncthreads();
    int c = 0;
#pragma unroll
    for (int k = 0; k < 32; k++) c += (idxs[t * 32 + k] == j);
    int v = c;
#pragma unroll
    for (int off = 1; off < 64; off <<= 1) {
        int o = __shfl_up(v, off, 64);
        if (lane >= off) v += o;
    }
    if (lane == 63) wsum[w] = v;
    __syncthreads();
    int wbase = 0;
#pragma unroll
    for (int i = 0; i < 4; i++) wbase += (i < w) ? wsum[i] : 0;
    int excl = wbase + v - c;
    int total = ((wsum[0] + wsum[1]) + (wsum[2] + wsum[3]));
    int pos = excl;
    for (int k = 0; k < 32; k++) {
        int tok = t * 32 + k;
        if (idxs[tok] == j && pos < 256) list[pos++] = tok;
    }
    __syncthreads();
    if (total > 256) total = 256;
    float nc = o_ncs[j];
    size_t rowoff = (size_t)j * DIM;
#pragma unroll
    for (int k = 0; k < 4; k++) {
        int d = t * 4 + 1024 * k;
        float sx = 0.f, sy = 0.f, sz = 0.f, sw = 0.f;
        for (int q = 0; q < total; q++) {
            float4 vv = *(const float4*)(inputs + (size_t)list[q] * DIM + d);
            sx += vv.x; sy += vv.y; sz += vv.z; sw += vv.w;
        }
        float4 w4 = *(const float4*)(ema_w + rowoff + d);
        float w0 = w4.x * 0.99f + 0.01f * sx;
        float w1 = w4.y * 0.99f + 0.01f * sy;
        float w2 = w4.z * 0.99f + 0.01f * sz;
        float w3 = w4.w * 0.99f + 0.01f * sw;
        o_neww[rowoff + d + 0] = w0; o_newemb[rowoff + d + 0] = w0 / nc;
        o_neww[rowoff + d + 1] = w1; o_newemb[rowoff + d + 1] = w1 / nc;
        o_neww[rowoff + d + 2] = w2; o_newemb[rowoff + d + 2] = w2 / nc;
        o_neww[rowoff + d + 3] = w3; o_newemb[rowoff + d + 3] = w3 / nc;
    }
}

// ---------------------------------------------------------------------------
extern "C" void kernel_launch(void* const* d_in, const int* in_sizes, int n_in,
                              void* d_out, int out_size, void* d_ws, size_t ws_size,
                              hipStream_t stream) {
    const float* inputs    = (const float*)d_in[0];
    const float* embedding = (const float*)d_in[1];
    const float* ema_w     = (const float*)d_in[2];
    const float* ema_cs    = (const float*)d_in[3];

    float* out = (float*)d_out;
    char* base = (char*)d_out;

    // scratch carved from d_out (lifetime-checked):
    // apk/bpk (fp8, 32MB each) dead after k_gemm; cand/enorms/counts/partials
    // parked inside o_neww region (written only by k_ema, last kernel).
    char* apk       = base;                            // [0, 32M)
    char* bpk       = base + 33554432;                 // [32M, 64M)
    u64* cand       = (u64*)(base + 167772160);        // 16 MB, dead after k_cand
    float* enorms   = (float*)(base + 184549376);      // 32 KB, dead after k_cand
    int* counts     = (int*)(base + 184582144);        // 32 KB, dead after k_csloss
    float* partials = (float*)(base + 184614912);      // 32 KB, dead after k_csloss

    // output regions (element offsets, return order)
    float* o_loss   = out;                 // [1]
    float* o_quant  = out + 1;             // [8192*4096]
    float* o_perp   = out + 33554433;      // [1]
    float* o_idx    = out + 33554434;      // [8192]
    float* o_ncs    = out + 33562626;      // [8192]
    float* o_neww   = out + 33570818;      // [8192*4096]
    float* o_newemb = out + 67125250;      // [8192*4096]

    k_pack<<<dim3(N_TOK + VOCAB), dim3(256), 0, stream>>>(inputs, embedding, apk, bpk,
                                                          enorms, counts);
    k_gemm<<<dim3(1024), dim3(512), 131072, stream>>>(apk, bpk, enorms, cand);
    k_cand<<<dim3(N_TOK), dim3(256), 0, stream>>>(cand, enorms, inputs, embedding,
                                                  o_idx, o_quant, partials, counts);
    k_csloss<<<dim3(2), dim3(1024), 0, stream>>>(counts, ema_cs, partials,
                                                 o_ncs, o_perp, o_loss);
    k_ema<<<dim3(VOCAB), dim3(256), 0, stream>>>(o_idx, inputs, ema_w, o_ncs, o_neww, o_newemb);
}